// Round 1
// baseline (6370.786 us; speedup 1.0000x reference)
//
#include <hip/hip_runtime.h>
#include <hip/hip_bf16.h>
#include <stdint.h>

#define BATCH 64
#define SEQ   512
#define INDIM 1024
#define HDIM  1024

typedef short bf16x8 __attribute__((ext_vector_type(8)));
typedef float f32x4  __attribute__((ext_vector_type(4)));

static __device__ __forceinline__ unsigned short f2bf(float x) {
  unsigned int u = __float_as_uint(x);
  u += 0x7fffu + ((u >> 16) & 1u);
  return (unsigned short)(u >> 16);
}
static __device__ __forceinline__ float bf2f(unsigned short b) {
  return __uint_as_float(((unsigned int)b) << 16);
}

// ---- split fp32 -> bf16 (hi, lo) ----
__global__ void split_kernel(const float* __restrict__ src, unsigned short* __restrict__ hi,
                             unsigned short* __restrict__ lo, int n) {
  int i = blockIdx.x * blockDim.x + threadIdx.x;
  if (i < n) {
    float x = src[i];
    unsigned short h = f2bf(x);
    hi[i] = h;
    lo[i] = f2bf(x - bf2f(h));
  }
}

// ---- phase 1: C[m][n] = sum_k A[m][k]*W[n][k] + bih[n] + bhh[n]  (fp32) ----
#define BK 32
__global__ __launch_bounds__(256) void xproj_kernel(const float* __restrict__ A,
                                                    const float* __restrict__ W,
                                                    const float* __restrict__ bih,
                                                    const float* __restrict__ bhh,
                                                    float* __restrict__ C) {
  __shared__ float As[64][BK + 1];
  __shared__ float Bs[64][BK + 1];
  const int m0 = blockIdx.x * 64;
  const int n0 = blockIdx.y * 64;
  const int tid = (int)threadIdx.x;
  const int tx = tid & 15, ty = tid >> 4;
  const int lr = tid >> 2, lc = (tid & 3) * 4;

  float c[4][4] = {};

  for (int k0 = 0; k0 < INDIM; k0 += BK) {
    float4 av0 = *(const float4*)(&A[(size_t)(m0 + lr) * INDIM + k0 + lc]);
    float4 av1 = *(const float4*)(&A[(size_t)(m0 + lr) * INDIM + k0 + lc + 16]);
    float4 bv0 = *(const float4*)(&W[(size_t)(n0 + lr) * INDIM + k0 + lc]);
    float4 bv1 = *(const float4*)(&W[(size_t)(n0 + lr) * INDIM + k0 + lc + 16]);
    As[lr][lc + 0] = av0.x; As[lr][lc + 1] = av0.y; As[lr][lc + 2] = av0.z; As[lr][lc + 3] = av0.w;
    As[lr][lc + 16] = av1.x; As[lr][lc + 17] = av1.y; As[lr][lc + 18] = av1.z; As[lr][lc + 19] = av1.w;
    Bs[lr][lc + 0] = bv0.x; Bs[lr][lc + 1] = bv0.y; Bs[lr][lc + 2] = bv0.z; Bs[lr][lc + 3] = bv0.w;
    Bs[lr][lc + 16] = bv1.x; Bs[lr][lc + 17] = bv1.y; Bs[lr][lc + 18] = bv1.z; Bs[lr][lc + 19] = bv1.w;
    __syncthreads();
#pragma unroll
    for (int kk = 0; kk < BK; ++kk) {
      float a0 = As[ty * 4 + 0][kk];
      float a1 = As[ty * 4 + 1][kk];
      float a2 = As[ty * 4 + 2][kk];
      float a3 = As[ty * 4 + 3][kk];
      float b0 = Bs[tx * 4 + 0][kk];
      float b1 = Bs[tx * 4 + 1][kk];
      float b2 = Bs[tx * 4 + 2][kk];
      float b3 = Bs[tx * 4 + 3][kk];
      c[0][0] += a0 * b0; c[0][1] += a0 * b1; c[0][2] += a0 * b2; c[0][3] += a0 * b3;
      c[1][0] += a1 * b0; c[1][1] += a1 * b1; c[1][2] += a1 * b2; c[1][3] += a1 * b3;
      c[2][0] += a2 * b0; c[2][1] += a2 * b1; c[2][2] += a2 * b2; c[2][3] += a2 * b3;
      c[3][0] += a3 * b0; c[3][1] += a3 * b1; c[3][2] += a3 * b2; c[3][3] += a3 * b3;
    }
    __syncthreads();
  }

  float bias[4];
#pragma unroll
  for (int j = 0; j < 4; ++j) {
    int n = n0 + tx * 4 + j;
    bias[j] = bih[n] + bhh[n];
  }
#pragma unroll
  for (int i = 0; i < 4; ++i) {
    int m = m0 + ty * 4 + i;
#pragma unroll
    for (int j = 0; j < 4; ++j) {
      C[(size_t)m * HDIM + n0 + tx * 4 + j] = c[i][j] + bias[j];
    }
  }
}

// ---- phase 2: one timestep.  h_new = relu(xp_t + h @ W_hh^T) via bf16 hi/lo split MFMA ----
__global__ __launch_bounds__(64) void rnn_step(const unsigned short* __restrict__ h_hi,
                                               const unsigned short* __restrict__ h_lo,
                                               const unsigned short* __restrict__ w_hi,
                                               const unsigned short* __restrict__ w_lo,
                                               float* __restrict__ out,
                                               unsigned short* __restrict__ nh_hi,
                                               unsigned short* __restrict__ nh_lo,
                                               int t) {
  const int lane = (int)threadIdx.x;      // 0..63, one wave per block
  const int mt = blockIdx.x & 3;          // 4 m-tiles (batch)
  const int nt = blockIdx.x >> 2;         // 64 n-tiles (hidden)
  const int m0 = mt * 16, n0 = nt * 16;
  const int r = lane & 15;
  const int kg = lane >> 4;               // 0..3

  f32x4 acc = {0.f, 0.f, 0.f, 0.f};
  const size_t arow = (size_t)(m0 + r) * HDIM;  // A frag: rows of h
  const size_t brow = (size_t)(n0 + r) * HDIM;  // B frag: rows of W_hh (gives W^T)

#pragma unroll 4
  for (int k0 = 0; k0 < HDIM; k0 += 32) {
    int ka = k0 + kg * 8;
    bf16x8 ah = *(const bf16x8*)(h_hi + arow + ka);
    bf16x8 al = *(const bf16x8*)(h_lo + arow + ka);
    bf16x8 bh = *(const bf16x8*)(w_hi + brow + ka);
    bf16x8 bl = *(const bf16x8*)(w_lo + brow + ka);
    acc = __builtin_amdgcn_mfma_f32_16x16x32_bf16(ah, bh, acc, 0, 0, 0);
    acc = __builtin_amdgcn_mfma_f32_16x16x32_bf16(ah, bl, acc, 0, 0, 0);
    acc = __builtin_amdgcn_mfma_f32_16x16x32_bf16(al, bh, acc, 0, 0, 0);
  }

  // D layout: col = lane&15, row = (lane>>4)*4 + q   [measured m89/m91]
  const int col = n0 + r;
#pragma unroll
  for (int q = 0; q < 4; ++q) {
    int row = m0 + kg * 4 + q;  // batch index
    size_t oidx = (size_t)row * SEQ * HDIM + (size_t)t * HDIM + col;
    float v = out[oidx] + acc[q];
    v = v > 0.f ? v : 0.f;
    out[oidx] = v;
    unsigned short hv = f2bf(v);
    nh_hi[row * HDIM + col] = hv;
    nh_lo[row * HDIM + col] = f2bf(v - bf2f(hv));
  }
}

// ---- h_n = outputs[:, SEQ-1, :] ----
__global__ void copy_hn(const float* __restrict__ out, float* __restrict__ hn) {
  int idx = blockIdx.x * blockDim.x + threadIdx.x;
  if (idx < BATCH * HDIM) {
    int b = idx >> 10, j = idx & 1023;
    hn[idx] = out[(size_t)b * SEQ * HDIM + (size_t)(SEQ - 1) * HDIM + j];
  }
}

extern "C" void kernel_launch(void* const* d_in, const int* in_sizes, int n_in,
                              void* d_out, int out_size, void* d_ws, size_t ws_size,
                              hipStream_t stream) {
  const float* inputs = (const float*)d_in[0];
  const float* h0     = (const float*)d_in[1];
  const float* w_ih   = (const float*)d_in[2];
  const float* w_hh   = (const float*)d_in[3];
  const float* b_ih   = (const float*)d_in[4];
  const float* b_hh   = (const float*)d_in[5];

  float* outBase = (float*)d_out;
  float* hnBase  = outBase + (size_t)BATCH * SEQ * HDIM;

  // ws layout: W_hh hi/lo (2 MB each) + 4 x 128 KB h ping-pong buffers
  unsigned short* w_hi = (unsigned short*)d_ws;
  unsigned short* w_lo = w_hi + (size_t)HDIM * HDIM;
  unsigned short* hb   = w_lo + (size_t)HDIM * HDIM;
  unsigned short* h_hi[2] = { hb,                hb + 2 * BATCH * HDIM };
  unsigned short* h_lo[2] = { hb + BATCH * HDIM, hb + 3 * BATCH * HDIM };

  split_kernel<<<(HDIM * HDIM + 255) / 256, 256, 0, stream>>>(w_hh, w_hi, w_lo, HDIM * HDIM);
  split_kernel<<<(BATCH * HDIM + 255) / 256, 256, 0, stream>>>(h0, h_hi[0], h_lo[0], BATCH * HDIM);

  dim3 g1(512, 16);
  xproj_kernel<<<g1, 256, 0, stream>>>(inputs, w_ih, b_ih, b_hh, outBase);

  for (int t = 0; t < SEQ; ++t) {
    int p = t & 1;
    rnn_step<<<256, 64, 0, stream>>>(h_hi[p], h_lo[p], w_hi, w_lo, outBase,
                                     h_hi[p ^ 1], h_lo[p ^ 1], t);
  }

  copy_hn<<<256, 256, 0, stream>>>(outBase, hnBase);
}